// Round 6
// baseline (186.668 us; speedup 1.0000x reference)
//
#include <hip/hip_runtime.h>

// RegionSelector two-phase: [B,1,512,512] f32 -> [B,1,2] int32 (row,col)
// argmax over 3x3 window sums of 4x4 grid-cell means. GRID=4, WIN=3 -> n=2,
// cell = 128x128. Mean's 1/16384 scale is argmax-invariant -> plain sums.
//
// History: all intra-kernel cross-workgroup sync costs 100-400us on CDNA4
// (R2 acquire-spin 457, R3 relaxed-spin 233, R4 ACQ_REL ticket 152). R5
// zero-sync 1-block/batch was clean but used only 128/256 CUs (~45us, per-CU
// BW ceiling ~24.6 GB/s). R6: the only cheap device-wide sync is the kernel
// boundary. Phase 1: 512 blocks (2/CU, full chip) each reduce one grid-row
// band (128 rows, 256KB) to 4 cell sums. Phase 2: 1 tiny block, argmax.

#define H 512
#define W 512

// Phase 1: block bid = b*4 + gr reduces rows [gr*128, gr*128+128) of batch b
// to the 4 cell sums of grid row gr. 1024 threads, 16 float4 loads each.
__global__ __launch_bounds__(1024, 2) void grid_row_sum(
    const float* __restrict__ src, float* __restrict__ partial) {
  const int bid = blockIdx.x;
  const int t = threadIdx.x;
  // Band base: bid * 128 rows * 512 cols (float4 view: 16384 per band).
  const float4* base = (const float4*)(src + (size_t)bid * (128 * W));

  // f = t + 1024*k: col4 = f & 127 = t & 127 constant per thread -> grid
  // column gc = (t & 127) >> 5 fixed; every width-32 shuffle segment shares
  // one gc (segment s covers cols4 [s*32 & 127 ...] -> gc = s & 3).
  float s = 0.0f;
#pragma unroll
  for (int k = 0; k < 16; ++k) {
    float4 v = base[t + 1024 * k];
    s += (v.x + v.y) + (v.z + v.w);
  }
#pragma unroll
  for (int off = 16; off > 0; off >>= 1) s += __shfl_down(s, off, 32);

  __shared__ float seg[32];  // [segment]; segment gc = seg & 3
  if ((t & 31) == 0) seg[t >> 5] = s;
  __syncthreads();

  if (t < 4) {
    float c = 0.0f;
#pragma unroll
    for (int j = 0; j < 8; ++j) c += seg[j * 4 + t];
    partial[bid * 4 + t] = c;  // partial[b][gr][gc]
  }
}

// Phase 2: one thread per batch. Read 16 cell sums, 3x3 window argmax.
__global__ __launch_bounds__(128) void select_region(
    const float* __restrict__ partial, int* __restrict__ out, int B) {
  const int b = blockIdx.x * blockDim.x + threadIdx.x;
  if (b >= B) return;
  const float* p = partial + (size_t)b * 16;  // [gr*4 + gc]

  // 3x3 window sums, n=2; strict '>' keeps lowest index on ties
  // (matches jax.lax.top_k).
  float best = -__builtin_inff();
  int bi = 0;
#pragma unroll
  for (int i = 0; i < 2; ++i)
#pragma unroll
    for (int j = 0; j < 2; ++j) {
      float ws = 0.0f;
#pragma unroll
      for (int di = 0; di < 3; ++di)
#pragma unroll
        for (int dj = 0; dj < 3; ++dj) ws += p[(i + di) * 4 + (j + dj)];
      if (ws > best) {
        best = ws;
        bi = i * 2 + j;
      }
    }
  out[b * 2 + 0] = bi >> 1;  // row
  out[b * 2 + 1] = bi & 1;   // col
}

extern "C" void kernel_launch(void* const* d_in, const int* in_sizes, int n_in,
                              void* d_out, int out_size, void* d_ws,
                              size_t ws_size, hipStream_t stream) {
  const float* src = (const float*)d_in[0];
  int* out = (int*)d_out;
  const int B = in_sizes[0] / (H * W);
  float* partial = (float*)d_ws;  // B*16 floats = 8 KB

  grid_row_sum<<<B * 4, 1024, 0, stream>>>(src, partial);
  select_region<<<(B + 127) / 128, 128, 0, stream>>>(partial, out, B);
}